// Round 3
// baseline (518.623 us; speedup 1.0000x reference)
//
#include <hip/hip_runtime.h>

#define C 64
#define RMAX 50
#define MAXD 64   // max degree supported (Poisson(10) over 100K heads -> max ~35)
#define LEAKY 0.2f

__device__ __forceinline__ float bf2f(unsigned short u) {
  return __uint_as_float(((unsigned)u) << 16);
}
__device__ __forceinline__ unsigned short f2bf(float x) {
  unsigned u = __float_as_uint(x);
  return (unsigned short)((u + 0x7FFFu + ((u >> 16) & 1u)) >> 16);  // RNE
}

// scalar float load with runtime dtype flag
__device__ __forceinline__ float loadF(const void* p, int i, int isbf) {
  return isbf ? bf2f(((const unsigned short*)p)[i]) : ((const float*)p)[i];
}
// index load with runtime width flag (int64 little-endian, values < 2^31)
__device__ __forceinline__ int loadI(const int* p, int e, int is64) {
  return is64 ? p[2 * e] : p[e];
}

// ---- dtype detection: flags[0]=float_is_bf16, flags[1]=eidx_is_64, flags[2]=etype_is_64 ----
__global__ void detect_kernel(const unsigned* __restrict__ entw,
                              const int* __restrict__ eidx,
                              const int* __restrict__ etype,
                              int* __restrict__ flags) {
  const int t = threadIdx.x;  // 64 threads
  int bfok = 0;
  for (int i = t; i < 256; i += 64) {
    unsigned w = entw[i];
    unsigned lo = w & 0xFFFFu;
    float a = fabsf(__uint_as_float(lo << 16));
    bfok += (lo == 0 || (a >= 1e-9f && a <= 1e9f)) ? 1 : 0;
  }
  int ez = (eidx[2 * t + 1] == 0) ? 1 : 0;
  int tz = (etype[2 * t + 1] == 0) ? 1 : 0;
#pragma unroll
  for (int d = 1; d < 64; d <<= 1) {
    bfok += __shfl_xor(bfok, d, 64);
    ez += __shfl_xor(ez, d, 64);
    tz += __shfl_xor(tz, d, 64);
  }
  if (t == 0) {
    flags[0] = (bfok >= 224) ? 1 : 0;
    flags[1] = (ez >= 62) ? 1 : 0;
    flags[2] = (tz >= 62) ? 1 : 0;
  }
}

// ---- precompute U[r]=W1^T rel_r, V[r]=W2^T rel_r, c[r]=rel_r . b ----
__global__ void uvc_kernel(const void* __restrict__ rel,
                           const void* __restrict__ fcw,
                           const void* __restrict__ fcb,
                           float* __restrict__ U, float* __restrict__ V,
                           float* __restrict__ cvec, const int* __restrict__ flags) {
  const int isbf = flags[0];
  const int r = blockIdx.x;
  const int i = threadIdx.x;  // 0..127
  float acc = 0.f;
  for (int o = 0; o < C; ++o)
    acc += loadF(rel, r * C + o, isbf) * loadF(fcw, o * (2 * C) + i, isbf);
  if (i < C) U[r * C + i] = acc;
  else       V[r * C + (i - C)] = acc;
  if (i < C) {  // threads 0..63 = wave 0 exactly
    float p = loadF(rel, r * C + i, isbf) * loadF(fcb, i, isbf);
#pragma unroll
    for (int d = 1; d < 64; d <<= 1) p += __shfl_xor(p, d, 64);
    if (i == 0) cvec[r] = p;
  }
}

// ---- CSR: degree count ----
__global__ void count_kernel(const int* __restrict__ eidx, int* __restrict__ deg,
                             int E, int N, const int* __restrict__ flags) {
  const int is64 = flags[1];
  int e = blockIdx.x * blockDim.x + threadIdx.x;
  if (e >= E) return;
  int h = loadI(eidx, e, is64);
  if ((unsigned)h >= (unsigned)N) h = 0;
  atomicAdd(&deg[h], 1);
}

// ---- CSR: exclusive scan (single block); rowoff written, deg becomes cursor ----
__global__ void scan_kernel(int* __restrict__ deg, int* __restrict__ rowoff, int N) {
  __shared__ int waveS[16];
  __shared__ int carryS;
  const int tid = threadIdx.x;
  const int lane = tid & 63;
  const int w = tid >> 6;
  if (tid == 0) carryS = 0;
  __syncthreads();
  for (int base = 0; base < N; base += 1024) {
    int i = base + tid;
    int v = (i < N) ? deg[i] : 0;
    int x = v;
#pragma unroll
    for (int d = 1; d < 64; d <<= 1) {
      int y = __shfl_up(x, d, 64);
      if (lane >= d) x += y;
    }
    if (lane == 63) waveS[w] = x;
    __syncthreads();
    if (tid == 0) {
      int run = carryS;
#pragma unroll
      for (int k = 0; k < 16; ++k) { int t = waveS[k]; waveS[k] = run; run += t; }
      carryS = run;
    }
    __syncthreads();
    int excl = x - v + waveS[w];
    if (i < N) { rowoff[i] = excl; deg[i] = excl; }
    __syncthreads();
  }
  if (tid == 0) rowoff[N] = carryS;
}

// ---- CSR: fill packed (tail | type<<20) ----
__global__ void fill_kernel(const int* __restrict__ eidx, const int* __restrict__ etype,
                            int* __restrict__ cursor, int* __restrict__ packed,
                            int E, int N, int Rc, const int* __restrict__ flags) {
  const int is64 = flags[1];
  const int et64 = flags[2];
  int e = blockIdx.x * blockDim.x + threadIdx.x;
  if (e >= E) return;
  int h = loadI(eidx, e, is64);
  int t = is64 ? eidx[2 * E + 2 * e] : eidx[E + e];
  int r = loadI(etype, e, et64);
  if ((unsigned)h >= (unsigned)N) h = 0;
  if ((unsigned)t >= (unsigned)N) t = 0;
  if ((unsigned)r >= (unsigned)Rc) r = 0;
  int pos = atomicAdd(&cursor[h], 1);
  if ((unsigned)pos < (unsigned)E) packed[pos] = t | (r << 20);
}

// ---- fused hop ----
// 16 lanes per node (lane owns 4 channels), 16 nodes per 256-thread block.
// IN_RAW: input is the raw entity buffer (dtype per flags[0]); else fp32 mid.
// OUT_RAW: output is d_out (dtype per flags[0]); else fp32 mid.
template <bool IN_RAW, bool OUT_RAW>
__global__ __launch_bounds__(256) void hop_kernel(
    const void* __restrict__ emb_in_v, void* __restrict__ emb_out_v,
    const int* __restrict__ rowoff, const int* __restrict__ packed,
    const float* __restrict__ Ug, const float* __restrict__ Vg,
    const float* __restrict__ cg, int N, int Rc, int E,
    const int* __restrict__ flags) {
  __shared__ float uS[RMAX * C];
  __shared__ float vS[RMAX * C];
  __shared__ float cS[RMAX];
  __shared__ float sS[16 * MAXD];
  const int isbf = flags[0];
  for (int i = threadIdx.x; i < Rc * C; i += 256) { uS[i] = Ug[i]; vS[i] = Vg[i]; }
  for (int i = threadIdx.x; i < Rc; i += 256) cS[i] = cg[i];
  __syncthreads();

  const int g = threadIdx.x >> 4;
  const int l = threadIdx.x & 15;
  const int n = blockIdx.x * 16 + g;
  if (n >= N) return;

  auto loadRow = [&](int row) -> float4 {
    if (IN_RAW && isbf) {
      ushort4 u = ((const ushort4*)emb_in_v)[(size_t)row * (C / 4) + l];
      float4 f; f.x = bf2f(u.x); f.y = bf2f(u.y); f.z = bf2f(u.z); f.w = bf2f(u.w);
      return f;
    }
    return ((const float4*)emb_in_v)[(size_t)row * (C / 4) + l];
  };

  int start = rowoff[n];
  int end   = rowoff[n + 1];
  if (start < 0) start = 0;
  if (start > E) start = E;
  int cnt = end - start;
  if (cnt < 0) cnt = 0;
  if (cnt > MAXD) cnt = MAXD;
  if (cnt > E - start) cnt = E - start;

  const float4 en = loadRow(n);

  // phase 1: scores -> LDS; running max (post-butterfly, every lane has full score)
  float m = -1e30f;
  for (int jj = 0; jj < cnt; ++jj) {
    unsigned pk = (unsigned)packed[start + jj];
    int t = (int)(pk & 0xFFFFFu); if (t >= N) t = 0;
    int r = (int)(pk >> 20);      if (r >= Rc) r = 0;
    const float4 uu = *(const float4*)&uS[r * C + l * 4];
    const float4 vv = *(const float4*)&vS[r * C + l * 4];
    const float4 et = loadRow(t);
    float p = uu.x * en.x + uu.y * en.y + uu.z * en.z + uu.w * en.w
            + vv.x * et.x + vv.y * et.y + vv.z * et.z + vv.w * et.w;
    p += __shfl_xor(p, 1); p += __shfl_xor(p, 2);
    p += __shfl_xor(p, 4); p += __shfl_xor(p, 8);
    float s = p + cS[r];
    s = s > 0.f ? s : LEAKY * s;
    if (l == 0) sS[g * MAXD + jj] = s;
    m = fmaxf(m, s);
  }

  // phase 2: softmax denominator
  float sum = 0.f;
  for (int jj = l; jj < cnt; jj += 16) sum += __expf(sS[g * MAXD + jj] - m);
  sum += __shfl_xor(sum, 1); sum += __shfl_xor(sum, 2);
  sum += __shfl_xor(sum, 4); sum += __shfl_xor(sum, 8);
  const float inv = (cnt > 0 && sum > 0.f) ? 1.0f / sum : 0.f;

  // phase 3: weighted aggregate + residual
  float4 acc = en;
  for (int jj = 0; jj < cnt; ++jj) {
    unsigned pk = (unsigned)packed[start + jj];
    int t = (int)(pk & 0xFFFFFu); if (t >= N) t = 0;
    float wgt = __expf(sS[g * MAXD + jj] - m) * inv;
    const float4 et = loadRow(t);
    acc.x += wgt * et.x; acc.y += wgt * et.y;
    acc.z += wgt * et.z; acc.w += wgt * et.w;
  }

  // L2 normalize: emb / max(||emb||, 1e-12)
  float ss = acc.x * acc.x + acc.y * acc.y + acc.z * acc.z + acc.w * acc.w;
  ss += __shfl_xor(ss, 1); ss += __shfl_xor(ss, 2);
  ss += __shfl_xor(ss, 4); ss += __shfl_xor(ss, 8);
  float sc = 1.0f / fmaxf(sqrtf(ss), 1e-12f);
  float4 o;
  o.x = acc.x * sc; o.y = acc.y * sc; o.z = acc.z * sc; o.w = acc.w * sc;
  if (OUT_RAW && isbf) {
    ushort4 u;
    u.x = f2bf(o.x); u.y = f2bf(o.y); u.z = f2bf(o.z); u.w = f2bf(o.w);
    ((ushort4*)emb_out_v)[(size_t)n * (C / 4) + l] = u;
  } else {
    ((float4*)emb_out_v)[(size_t)n * (C / 4) + l] = o;
  }
}

extern "C" void kernel_launch(void* const* d_in, const int* in_sizes, int n_in,
                              void* d_out, int out_size, void* d_ws, size_t ws_size,
                              hipStream_t stream) {
  const void* ent  = d_in[0];             // [N,C] fp32 or bf16 (detected)
  const void* rel  = d_in[1];             // [R,C]
  const void* fcw  = d_in[2];             // [C,2C]
  const void* fcb  = d_in[3];             // [C]
  const int* eidx  = (const int*)d_in[4]; // [2,E] int32 or int64 (detected)
  const int* etype = (const int*)d_in[5]; // [E]

  const int N  = in_sizes[0] / C;
  const int R0 = in_sizes[1] / C;
  const int Rc = R0 < RMAX ? R0 : RMAX;
  const int E  = in_sizes[5];
  (void)n_in; (void)out_size;

  char* ws = (char*)d_ws;
  size_t off = 0;
  auto alloc = [&](size_t bytes) -> void* {
    void* p = ws + off;
    off = (off + bytes + 255) & ~(size_t)255;
    return p;
  };
  int*   flags  = (int*)alloc(64);
  float* U      = (float*)alloc((size_t)Rc * C * 4);
  float* V      = (float*)alloc((size_t)Rc * C * 4);
  float* cv     = (float*)alloc((size_t)Rc * 4);
  char*  int_base = ws + off;
  int*   deg    = (int*)alloc((size_t)N * 4);         // doubles as fill cursor
  int*   rowoff = (int*)alloc((size_t)(N + 1) * 4);
  int*   packed = (int*)alloc((size_t)E * 4);
  size_t int_bytes = (ws + off) - int_base;
  float* mid    = (float*)alloc((size_t)N * C * 4);   // fp32 canonical intermediate
  (void)ws_size;

  hipMemsetAsync(int_base, 0, int_bytes, stream);
  detect_kernel<<<1, 64, 0, stream>>>((const unsigned*)ent, eidx, etype, flags);
  uvc_kernel<<<Rc, 128, 0, stream>>>(rel, fcw, fcb, U, V, cv, flags);
  count_kernel<<<(E + 255) / 256, 256, 0, stream>>>(eidx, deg, E, N, flags);
  scan_kernel<<<1, 1024, 0, stream>>>(deg, rowoff, N);
  fill_kernel<<<(E + 255) / 256, 256, 0, stream>>>(eidx, etype, deg, packed, E, N, Rc, flags);

  const int hb = (N + 15) / 16;
  hop_kernel<true,  false><<<hb, 256, 0, stream>>>(ent, mid,   rowoff, packed, U, V, cv, N, Rc, E, flags);
  hop_kernel<false, true ><<<hb, 256, 0, stream>>>(mid, d_out, rowoff, packed, U, V, cv, N, Rc, E, flags);
}

// Round 4
// 326.013 us; speedup vs baseline: 1.5908x; 1.5908x over previous
//
#include <hip/hip_runtime.h>

#define C 64
#define RMAX 50
#define LEAKY 0.2f

__device__ __forceinline__ float bf2f(unsigned short u) {
  return __uint_as_float(((unsigned)u) << 16);
}
__device__ __forceinline__ unsigned short f2bf(float x) {
  unsigned u = __float_as_uint(x);
  return (unsigned short)((u + 0x7FFFu + ((u >> 16) & 1u)) >> 16);  // RNE
}
__device__ __forceinline__ float loadF(const void* p, int i, int isbf) {
  return isbf ? bf2f(((const unsigned short*)p)[i]) : ((const float*)p)[i];
}
__device__ __forceinline__ int loadI(const int* p, int e, int is64) {
  return is64 ? p[2 * e] : p[e];
}

// ---- dtype detection: flags[0]=float_is_bf16, flags[1]=eidx_is_64, flags[2]=etype_is_64 ----
__global__ void detect_kernel(const unsigned* __restrict__ entw,
                              const int* __restrict__ eidx,
                              const int* __restrict__ etype,
                              int* __restrict__ flags) {
  const int t = threadIdx.x;  // 64 threads
  int bfok = 0;
  for (int i = t; i < 256; i += 64) {
    unsigned w = entw[i];
    unsigned lo = w & 0xFFFFu;
    float a = fabsf(__uint_as_float(lo << 16));
    bfok += (lo == 0 || (a >= 1e-9f && a <= 1e9f)) ? 1 : 0;
  }
  int ez = (eidx[2 * t + 1] == 0) ? 1 : 0;
  int tz = (etype[2 * t + 1] == 0) ? 1 : 0;
#pragma unroll
  for (int d = 1; d < 64; d <<= 1) {
    bfok += __shfl_xor(bfok, d, 64);
    ez += __shfl_xor(ez, d, 64);
    tz += __shfl_xor(tz, d, 64);
  }
  if (t == 0) {
    flags[0] = (bfok >= 224) ? 1 : 0;
    flags[1] = (ez >= 62) ? 1 : 0;
    flags[2] = (tz >= 62) ? 1 : 0;
  }
}

// ---- precompute U[r]=W1^T rel_r, V[r]=W2^T rel_r, c[r]=rel_r . b ----
__global__ void uvc_kernel(const void* __restrict__ rel,
                           const void* __restrict__ fcw,
                           const void* __restrict__ fcb,
                           float* __restrict__ U, float* __restrict__ V,
                           float* __restrict__ cvec, const int* __restrict__ flags) {
  const int isbf = flags[0];
  const int r = blockIdx.x;
  const int i = threadIdx.x;  // 0..127
  float acc = 0.f;
  for (int o = 0; o < C; ++o)
    acc += loadF(rel, r * C + o, isbf) * loadF(fcw, o * (2 * C) + i, isbf);
  if (i < C) U[r * C + i] = acc;
  else       V[r * C + (i - C)] = acc;
  if (i < C) {  // threads 0..63 = wave 0 exactly
    float p = loadF(rel, r * C + i, isbf) * loadF(fcb, i, isbf);
#pragma unroll
    for (int d = 1; d < 64; d <<= 1) p += __shfl_xor(p, d, 64);
    if (i == 0) cvec[r] = p;
  }
}

// ---- CSR: degree count ----
__global__ void count_kernel(const int* __restrict__ eidx, int* __restrict__ deg,
                             int E, int N, const int* __restrict__ flags) {
  const int is64 = flags[1];
  int e = blockIdx.x * blockDim.x + threadIdx.x;
  if (e >= E) return;
  int h = loadI(eidx, e, is64);
  if ((unsigned)h >= (unsigned)N) h = 0;
  atomicAdd(&deg[h], 1);
}

// ---- multi-block exclusive scan: A (local) -> B (block sums) -> C (combine) ----
__global__ void scanA_kernel(const int* __restrict__ deg, int* __restrict__ loc,
                             int* __restrict__ bsum, int N) {
  __shared__ int waveS[16];
  __shared__ int totS;
  const int tid = threadIdx.x, lane = tid & 63, w = tid >> 6;
  const int i = blockIdx.x * 1024 + tid;
  int v = (i < N) ? deg[i] : 0;
  int x = v;
#pragma unroll
  for (int d = 1; d < 64; d <<= 1) {
    int y = __shfl_up(x, d, 64);
    if (lane >= d) x += y;
  }
  if (lane == 63) waveS[w] = x;
  __syncthreads();
  if (tid == 0) {
    int run = 0;
#pragma unroll
    for (int k = 0; k < 16; ++k) { int t = waveS[k]; waveS[k] = run; run += t; }
    totS = run;
  }
  __syncthreads();
  if (i < N) loc[i] = x - v + waveS[w];
  if (tid == 0) bsum[blockIdx.x] = totS;
}

__global__ void scanB_kernel(int* __restrict__ bsum, int nb, int* __restrict__ totOut) {
  __shared__ int waveS[16];
  __shared__ int carryS;
  const int tid = threadIdx.x, lane = tid & 63, w = tid >> 6;
  if (tid == 0) carryS = 0;
  __syncthreads();
  for (int base = 0; base < nb; base += 1024) {
    int i = base + tid;
    int v = (i < nb) ? bsum[i] : 0;
    int x = v;
#pragma unroll
    for (int d = 1; d < 64; d <<= 1) {
      int y = __shfl_up(x, d, 64);
      if (lane >= d) x += y;
    }
    if (lane == 63) waveS[w] = x;
    __syncthreads();
    if (tid == 0) {
      int run = carryS;
#pragma unroll
      for (int k = 0; k < 16; ++k) { int t = waveS[k]; waveS[k] = run; run += t; }
      carryS = run;
    }
    __syncthreads();
    if (i < nb) bsum[i] = x - v + waveS[w];
    __syncthreads();
  }
  if (tid == 0) *totOut = carryS;
}

__global__ void scanC_kernel(const int* __restrict__ loc, const int* __restrict__ bsum,
                             int* __restrict__ rowoff, int* __restrict__ cursor, int N) {
  const int i = blockIdx.x * 1024 + threadIdx.x;
  if (i < N) {
    int v = loc[i] + bsum[blockIdx.x];
    rowoff[i] = v;
    cursor[i] = v;
  }
}

// ---- CSR: fill packed (tail | type<<20) ----
__global__ void fill_kernel(const int* __restrict__ eidx, const int* __restrict__ etype,
                            int* __restrict__ cursor, int* __restrict__ packed,
                            int E, int N, int Rc, const int* __restrict__ flags) {
  const int is64 = flags[1];
  const int et64 = flags[2];
  int e = blockIdx.x * blockDim.x + threadIdx.x;
  if (e >= E) return;
  int h = loadI(eidx, e, is64);
  int t = is64 ? eidx[2 * E + 2 * e] : eidx[E + e];
  int r = loadI(etype, e, et64);
  if ((unsigned)h >= (unsigned)N) h = 0;
  if ((unsigned)t >= (unsigned)N) t = 0;
  if ((unsigned)r >= (unsigned)Rc) r = 0;
  int pos = atomicAdd(&cursor[h], 1);
  if ((unsigned)pos < (unsigned)E) packed[pos] = t | (r << 20);
}

// ---- fused hop: single-pass online-softmax aggregate, LDS-free, barrier-free ----
// 16 lanes per node (lane owns 4 channels), 16 nodes per 256-thread block.
template <bool IN_RAW, bool OUT_RAW>
__global__ __launch_bounds__(256) void hop_kernel(
    const void* __restrict__ emb_in_v, void* __restrict__ emb_out_v,
    const int* __restrict__ rowoff, const int* __restrict__ packed,
    const float* __restrict__ Ug, const float* __restrict__ Vg,
    const float* __restrict__ cg, int N, int Rc, int E,
    const int* __restrict__ flags) {
  const int isbf = flags[0];
  const int g = threadIdx.x >> 4;
  const int l = threadIdx.x & 15;
  const int n = blockIdx.x * 16 + g;
  if (n >= N) return;

  auto loadRow = [&](int row) -> float4 {
    if (IN_RAW && isbf) {
      ushort4 u = ((const ushort4*)emb_in_v)[(size_t)row * (C / 4) + l];
      float4 f; f.x = bf2f(u.x); f.y = bf2f(u.y); f.z = bf2f(u.z); f.w = bf2f(u.w);
      return f;
    }
    return ((const float4*)emb_in_v)[(size_t)row * (C / 4) + l];
  };

  int start = rowoff[n];
  int end   = rowoff[n + 1];
  if (start < 0) start = 0;
  if (start > E) start = E;
  int cnt = end - start;
  if (cnt < 0) cnt = 0;
  if (cnt > E - start) cnt = E - start;

  const float4 en = loadRow(n);

  float m = -1e30f, lsum = 0.f;
  float4 acc; acc.x = acc.y = acc.z = acc.w = 0.f;

  // one-edge lookahead pipeline
  float4 et, uu, vv; float cb = 0.f;
  auto issue = [&](unsigned pkv) {
    int t = (int)(pkv & 0xFFFFFu); if (t >= N) t = 0;
    int r = (int)(pkv >> 20);      if (r >= Rc) r = 0;
    et = loadRow(t);
    uu = *(const float4*)&Ug[r * C + l * 4];
    vv = *(const float4*)&Vg[r * C + l * 4];
    cb = cg[r];
  };
  if (cnt > 0) issue((unsigned)packed[start]);

  for (int jj = 0; jj < cnt; ++jj) {
    const float4 cet = et, cuu = uu, cvv = vv;
    const float cc = cb;
    if (jj + 1 < cnt) issue((unsigned)packed[start + jj + 1]);
    float p = cuu.x * en.x + cuu.y * en.y + cuu.z * en.z + cuu.w * en.w
            + cvv.x * cet.x + cvv.y * cet.y + cvv.z * cet.z + cvv.w * cet.w;
    p += __shfl_xor(p, 1); p += __shfl_xor(p, 2);
    p += __shfl_xor(p, 4); p += __shfl_xor(p, 8);
    float s = p + cc;
    s = s > 0.f ? s : LEAKY * s;
    const float mn = fmaxf(m, s);
    const float alpha = __expf(m - mn);   // m=-1e30 first iter -> alpha=0
    const float wgt = __expf(s - mn);
    lsum = lsum * alpha + wgt;
    acc.x = acc.x * alpha + wgt * cet.x;
    acc.y = acc.y * alpha + wgt * cet.y;
    acc.z = acc.z * alpha + wgt * cet.z;
    acc.w = acc.w * alpha + wgt * cet.w;
    m = mn;
  }

  const float inv = (cnt > 0) ? 1.0f / lsum : 0.f;  // lsum >= 1 when cnt>0
  float4 o;
  o.x = acc.x * inv + en.x;
  o.y = acc.y * inv + en.y;
  o.z = acc.z * inv + en.z;
  o.w = acc.w * inv + en.w;

  // L2 normalize: emb / max(||emb||, 1e-12)
  float ss = o.x * o.x + o.y * o.y + o.z * o.z + o.w * o.w;
  ss += __shfl_xor(ss, 1); ss += __shfl_xor(ss, 2);
  ss += __shfl_xor(ss, 4); ss += __shfl_xor(ss, 8);
  const float sc = 1.0f / fmaxf(sqrtf(ss), 1e-12f);
  o.x *= sc; o.y *= sc; o.z *= sc; o.w *= sc;

  if (OUT_RAW && isbf) {
    ushort4 u;
    u.x = f2bf(o.x); u.y = f2bf(o.y); u.z = f2bf(o.z); u.w = f2bf(o.w);
    ((ushort4*)emb_out_v)[(size_t)n * (C / 4) + l] = u;
  } else {
    ((float4*)emb_out_v)[(size_t)n * (C / 4) + l] = o;
  }
}

extern "C" void kernel_launch(void* const* d_in, const int* in_sizes, int n_in,
                              void* d_out, int out_size, void* d_ws, size_t ws_size,
                              hipStream_t stream) {
  const void* ent  = d_in[0];             // [N,C] fp32 or bf16 (detected)
  const void* rel  = d_in[1];             // [R,C]
  const void* fcw  = d_in[2];             // [C,2C]
  const void* fcb  = d_in[3];             // [C]
  const int* eidx  = (const int*)d_in[4]; // [2,E] int32 or int64 (detected)
  const int* etype = (const int*)d_in[5]; // [E]

  const int N  = in_sizes[0] / C;
  const int R0 = in_sizes[1] / C;
  const int Rc = R0 < RMAX ? R0 : RMAX;
  const int E  = in_sizes[5];
  (void)n_in; (void)out_size; (void)ws_size;

  char* ws = (char*)d_ws;
  size_t off = 0;
  auto alloc = [&](size_t bytes) -> void* {
    void* p = ws + off;
    off = (off + bytes + 255) & ~(size_t)255;
    return p;
  };
  int*   flags  = (int*)alloc(64);
  float* U      = (float*)alloc((size_t)Rc * C * 4);
  float* V      = (float*)alloc((size_t)Rc * C * 4);
  float* cv     = (float*)alloc((size_t)Rc * 4);
  int*   deg    = (int*)alloc((size_t)N * 4);         // degrees, then fill-cursor
  int*   rowoff = (int*)alloc((size_t)(N + 1) * 4);
  int*   loc    = (int*)alloc((size_t)N * 4);         // local scan values
  int*   bsum   = (int*)alloc(((size_t)(N + 1023) / 1024 + 1) * 4);
  int*   packed = (int*)alloc((size_t)E * 4);
  float* mid    = (float*)alloc((size_t)N * C * 4);   // fp32 canonical intermediate

  const int nb = (N + 1023) / 1024;

  hipMemsetAsync(deg, 0, (size_t)N * 4, stream);
  detect_kernel<<<1, 64, 0, stream>>>((const unsigned*)ent, eidx, etype, flags);
  uvc_kernel<<<Rc, 128, 0, stream>>>(rel, fcw, fcb, U, V, cv, flags);
  count_kernel<<<(E + 255) / 256, 256, 0, stream>>>(eidx, deg, E, N, flags);
  scanA_kernel<<<nb, 1024, 0, stream>>>(deg, loc, bsum, N);
  scanB_kernel<<<1, 1024, 0, stream>>>(bsum, nb, &rowoff[N]);
  scanC_kernel<<<nb, 1024, 0, stream>>>(loc, bsum, rowoff, deg, N);
  fill_kernel<<<(E + 255) / 256, 256, 0, stream>>>(eidx, etype, deg, packed, E, N, Rc, flags);

  const int hb = (N + 15) / 16;
  hop_kernel<true,  false><<<hb, 256, 0, stream>>>(ent, mid,   rowoff, packed, U, V, cv, N, Rc, E, flags);
  hop_kernel<false, true ><<<hb, 256, 0, stream>>>(mid, d_out, rowoff, packed, U, V, cv, N, Rc, E, flags);
}